// Round 3
// baseline (442.798 us; speedup 1.0000x reference)
//
#include <hip/hip_runtime.h>
#include <hip/hip_bf16.h>

#define MODEL 2048
#define NHEAD 16
#define HDIM  128
#define BB    2
#define LL    2048
#define N1    (3*MODEL)      // 6144
#define MTOT  (BB*LL)        // 4096

typedef __hip_bfloat16 bf16;
typedef __attribute__((ext_vector_type(8))) short bf16x8;
typedef __attribute__((ext_vector_type(4))) float f32x4;

static __device__ __forceinline__ f32x4 mfma16(bf16x8 a, bf16x8 b, f32x4 c) {
  return __builtin_amdgcn_mfma_f32_16x16x32_bf16(a, b, c, 0, 0, 0);
}

// async global->LDS DMA, 16B per lane; LDS base wave-uniform, dest linear
static __device__ __forceinline__ void gl_lds16(const void* g, void* l) {
  __builtin_amdgcn_global_load_lds(
      (const __attribute__((address_space(1))) unsigned int*)g,
      (__attribute__((address_space(3))) unsigned int*)l, 16, 0, 0);
}

// ---------------- prep: f32 -> bf16 (vectorized x4) ----------------
__global__ void k_cvt(const float* __restrict__ in, bf16* __restrict__ out, int n4) {
  int i = blockIdx.x * blockDim.x + threadIdx.x;
  if (i < n4) {
    float4 v = ((const float4*)in)[i];
    bf16* o = out + (size_t)i * 4;
    o[0] = __float2bfloat16(v.x);
    o[1] = __float2bfloat16(v.y);
    o[2] = __float2bfloat16(v.z);
    o[3] = __float2bfloat16(v.w);
  }
}

// ---------------- prep: transpose f32 [R][C] -> bf16 [C][R] ----------------
__global__ __launch_bounds__(256)
void k_transpose(const float* __restrict__ in, bf16* __restrict__ out, int R, int C) {
  __shared__ float t[32][33];
  const int c0 = blockIdx.x * 32, r0 = blockIdx.y * 32;
  const int tx = threadIdx.x & 31;
  const int ty = threadIdx.x >> 5;   // 0..7
#pragma unroll
  for (int i = 0; i < 4; ++i)
    t[ty + 8*i][tx] = in[(size_t)(r0 + ty + 8*i) * C + c0 + tx];
  __syncthreads();
#pragma unroll
  for (int i = 0; i < 4; ++i)
    out[(size_t)(c0 + ty + 8*i) * R + r0 + tx] = __float2bfloat16(t[tx][ty + 8*i]);
}

// ============ 256x256 8-phase GEMM (HK schedule in plain HIP) ============
// C = A[M][K] * BT[N][K]^T. BK=64 per K-tile, 2 K-tiles per iter, 8 phases.
// LDS 128KB dynamic: A: [2buf][2half][128][64] @0, B same @65536.
// st_16x32 swizzle: read addr ^= ((lin>>9)&1)<<5 ; staged via lane-permuted
// global source (lane^2 for lanes>=32) with linear gl_lds dest.
// EPI==1: RoPE + scatter Q/K row-major + V^T ; EPI==2: bias + f32 out.

#define BARRIER __builtin_amdgcn_s_barrier()
#define WAIT_LGKM0 { asm volatile("s_waitcnt lgkmcnt(0)" ::: "memory"); __builtin_amdgcn_sched_barrier(0); }
#define WAIT_VM4   { asm volatile("s_waitcnt vmcnt(4)"   ::: "memory"); __builtin_amdgcn_sched_barrier(0); }
#define PRIO1 __builtin_amdgcn_s_setprio(1)
#define PRIO0 __builtin_amdgcn_s_setprio(0)

#define RDA(P, MF0) \
  _Pragma("unroll") for (int q = 0; q < 4; ++q) { \
    aF[(MF0)+q][0] = *(const bf16x8*)(smem + (P) + aOff0 + ((MF0)+q)*2048); \
    aF[(MF0)+q][1] = *(const bf16x8*)(smem + (P) + aOff0 + ((MF0)+q)*2048 + 64); }
#define RDB(P, NF0) \
  _Pragma("unroll") for (int q = 0; q < 2; ++q) { \
    bF[(NF0)+q][0] = *(const bf16x8*)(smem + (P) + bOff0 + ((NF0)+q)*2048); \
    bF[(NF0)+q][1] = *(const bf16x8*)(smem + (P) + bOff0 + ((NF0)+q)*2048 + 64); }

#define MMQ(MF0, NF0) \
  _Pragma("unroll") for (int m_ = (MF0); m_ < (MF0)+4; ++m_) \
  _Pragma("unroll") for (int n_ = (NF0); n_ < (NF0)+2; ++n_) { \
    acc[m_][n_] = mfma16(aF[m_][0], bF[n_][0], acc[m_][n_]); \
    acc[m_][n_] = mfma16(aF[m_][1], bF[n_][1], acc[m_][n_]); }

#define STAGE_A(D, H, KT) { \
    const bf16* g_ = AsrcL + (size_t)(H)*128*Kd + (size_t)(KT)*64; \
    gl_lds16(g_,                  smem + ldsAw + (D)*32768 + (H)*16384); \
    gl_lds16(g_ + (size_t)64*Kd,  smem + ldsAw + (D)*32768 + (H)*16384 + 8192); }
#define STAGE_B(D, H, KT) { \
    const bf16* g_ = BsrcL + (size_t)(H)*128*Kd + (size_t)(KT)*64; \
    gl_lds16(g_,                  smem + ldsBw + (D)*32768 + (H)*16384); \
    gl_lds16(g_ + (size_t)64*Kd,  smem + ldsBw + (D)*32768 + (H)*16384 + 8192); }

template<int EPI>
__global__ __launch_bounds__(512, 2)
void k_gemm8(const bf16* __restrict__ A, const bf16* __restrict__ BT,
             int M, int N, int K,
             float* __restrict__ Cout, const float* __restrict__ bias,
             bf16* __restrict__ Qb, bf16* __restrict__ Kb, bf16* __restrict__ VTb,
             const float* __restrict__ cosT, const float* __restrict__ sinT)
{
  extern __shared__ char smem[];      // 131072 B
  const int Kd = K;
  const int tid = threadIdx.x;
  const int wid = tid >> 6, lane = tid & 63;
  const int wm = wid >> 2, wn = wid & 3;       // wave grid 2(M) x 4(N)
  const int lr = lane & 15, lkg = lane >> 4;
  const int m0 = blockIdx.y * 256, n0 = blockIdx.x * 256;

  // staging lane geometry (inverse-swizzled source)
  const int l2   = lane ^ (((lane >> 5) & 1) << 1);
  const int srow = l2 >> 3;            // 0..7
  const int scol = (l2 & 7) * 8;       // bf16 elems
  const bf16* AsrcL = A  + (size_t)(m0 + wid*8 + srow) * Kd + scol;
  const bf16* BsrcL = BT + (size_t)(n0 + wid*8 + srow) * Kd + scol;
  const int ldsAw = wid * 1024;
  const int ldsBw = 65536 + wid * 1024;

  // ds_read base offsets (swizzle depends only on lr)
  const int swzbit = ((lr >> 2) & 1) << 5;
  const int aOff0 = wm*16384 + ((lr*128 + lkg*16) ^ swzbit);
  const int bOff0 = 65536 + (wn >> 1)*16384 + ((((wn & 1)*64 + lr)*128 + lkg*16) ^ swzbit);

  const f32x4 vzero = {0.f, 0.f, 0.f, 0.f};
  f32x4 acc[8][4];
#pragma unroll
  for (int i = 0; i < 8; ++i)
#pragma unroll
    for (int j = 0; j < 4; ++j) acc[i][j] = vzero;
  bf16x8 aF[8][2], bF[4][2];

  const int nt = K >> 6;          // K-tiles of 64
  const int nIter = nt >> 1;

  // prologue: tile0 (A+B) + tile1 (A)
  STAGE_A(0,0,0) STAGE_A(0,1,0) STAGE_B(0,0,0) STAGE_B(0,1,0)
  STAGE_A(1,0,1) STAGE_A(1,1,1)
  WAIT_VM4; BARRIER;

  for (int i = 0; i < nIter; ++i) {
    const int to = 2*i + 1;
    int t2 = 2*i + 2; if (t2 >= nt) t2 = nt - 1;   // clamped: data unused
    int t3 = 2*i + 3; if (t3 >= nt) t3 = nt - 1;
    // ---- tile e = 2i from buf0 ----
    RDA(0,0) RDB(0,0) STAGE_B(1,0,to)                       // ph1
    BARRIER; WAIT_LGKM0; PRIO1; MMQ(0,0); PRIO0; BARRIER;
    RDA(0,4) RDB(0,2) STAGE_B(1,1,to)                       // ph2
    BARRIER; WAIT_LGKM0; PRIO1; MMQ(4,2); PRIO0; BARRIER;
    STAGE_A(0,0,t2)                                         // ph3
    BARRIER; PRIO1; MMQ(0,2); PRIO0; BARRIER;
    STAGE_A(0,1,t2)                                         // ph4
    BARRIER; PRIO1; MMQ(4,0); PRIO0; WAIT_VM4; BARRIER;
    // ---- tile o = 2i+1 from buf1 ----
    RDA(32768,0) RDB(32768,0) STAGE_B(0,0,t2)               // ph5
    BARRIER; WAIT_LGKM0; PRIO1; MMQ(0,0); PRIO0; BARRIER;
    RDA(32768,4) RDB(32768,2) STAGE_B(0,1,t2)               // ph6
    BARRIER; WAIT_LGKM0; PRIO1; MMQ(4,2); PRIO0; BARRIER;
    STAGE_A(1,0,t3)                                         // ph7
    BARRIER; PRIO1; MMQ(0,2); PRIO0; BARRIER;
    STAGE_A(1,1,t3)                                         // ph8
    BARRIER; PRIO1; MMQ(4,0); PRIO0; WAIT_VM4; BARRIER;
  }

  if constexpr (EPI == 1) {
    const float inv_sqrt_d = 0.08838834764831845f;  // 1/sqrt(128)
#pragma unroll
    for (int nf = 0; nf < 4; ++nf) {
      const int gcb = n0 + wn*64 + nf*16;           // wave-uniform, mult of 16
      const int section = gcb >> 11;                // 0=q 1=k 2=v
      const int cc = (gcb & 2047) + lr;
      const int h = cc >> 7, d = cc & 127;
#pragma unroll
      for (int mf = 0; mf < 8; ++mf) {
#pragma unroll
        for (int reg = 0; reg < 4; ++reg) {
          const int grow = m0 + wm*128 + mf*16 + lkg*4 + reg;
          const int bidx = grow >> 11, lseq = grow & 2047;
          float val = acc[mf][nf][reg];
          if (section < 2) {
            float p = __shfl_xor(val, 1);           // RoPE pair partner
            const int fi = d >> 1;
            float cv = cosT[(size_t)lseq * 64 + fi];
            float sv = sinT[(size_t)lseq * 64 + fi];
            float r = (d & 1) ? fmaf(p, sv, val * cv)
                              : fmaf(val, cv, -p * sv);
            if (section == 0) {
              r *= inv_sqrt_d;
              Qb[((size_t)(bidx*NHEAD + h) * LL + lseq) * HDIM + d] = __float2bfloat16(r);
            } else {
              Kb[((size_t)(bidx*NHEAD + h) * LL + lseq) * HDIM + d] = __float2bfloat16(r);
            }
          } else {
            VTb[((size_t)(bidx*NHEAD + h) * HDIM + d) * LL + lseq] = __float2bfloat16(val);
          }
        }
      }
    }
  } else {
#pragma unroll
    for (int nf = 0; nf < 4; ++nf) {
      const int gcol = n0 + wn*64 + nf*16 + lr;
      const float bv = bias[gcol];
#pragma unroll
      for (int mf = 0; mf < 8; ++mf) {
#pragma unroll
        for (int reg = 0; reg < 4; ++reg) {
          const int grow = m0 + wm*128 + mf*16 + lkg*4 + reg;
          Cout[(size_t)grow * N + gcol] = acc[mf][nf][reg] + bv;
        }
      }
    }
  }
}

// ---------------- flash attention (unchanged from round 2) ----------------
__global__ __launch_bounds__(256, 2)
void k_attn(const bf16* __restrict__ Qb, const bf16* __restrict__ Kb,
            const bf16* __restrict__ VTb, bf16* __restrict__ attnA)
{
  __shared__ bf16 Ks[64][136];
  __shared__ bf16 Vs[128][72];
  __shared__ bf16 Ps[4][32][72];

  const int bh  = blockIdx.y;
  const int qb  = (gridDim.x - 1) - blockIdx.x;
  const int tid = threadIdx.x;
  const int wid = tid >> 6, lane = tid & 63;
  const int lr  = lane & 15, lkg = lane >> 4;
  const int Q0  = qb * 128;
  const int q0w = Q0 + wid * 32;

  const bf16* Qh = Qb  + (size_t)bh * LL * HDIM;
  const bf16* Kh = Kb  + (size_t)bh * LL * HDIM;
  const bf16* Vh = VTb + (size_t)bh * HDIM * LL;

  const f32x4 vzero = {0.f, 0.f, 0.f, 0.f};
  bf16x8 qf[2][4];
#pragma unroll
  for (int qr = 0; qr < 2; ++qr)
#pragma unroll
    for (int kk = 0; kk < 4; ++kk)
      qf[qr][kk] = *(const bf16x8*)(Qh + (size_t)(q0w + qr*16 + lr) * HDIM + kk*32 + lkg*8);

  f32x4 oacc[2][8];
#pragma unroll
  for (int qr = 0; qr < 2; ++qr)
#pragma unroll
    for (int db = 0; db < 8; ++db) oacc[qr][db] = vzero;
  float mrow[2][4], lrow[2][4];
#pragma unroll
  for (int qr = 0; qr < 2; ++qr)
#pragma unroll
    for (int r = 0; r < 4; ++r) { mrow[qr][r] = -INFINITY; lrow[qr][r] = 0.f; }

  const int NT = Q0 / 64 + 2;
  bf16x8 kpre[4], vpre[4];
#pragma unroll
  for (int j = 0; j < 4; ++j) {
    const int c = j*256 + tid;
    kpre[j] = *(const bf16x8*)(Kh + (size_t)(c >> 4) * HDIM + (c & 15) * 8);
    vpre[j] = *(const bf16x8*)(Vh + (size_t)(c >> 3) * LL + (c & 7) * 8);
  }

  for (int kt = 0; kt < NT; ++kt) {
    const int kbase = kt * 64;
    __syncthreads();
#pragma unroll
    for (int j = 0; j < 4; ++j) {
      const int c = j*256 + tid;
      *(bf16x8*)&Ks[c >> 4][(c & 15) * 8] = kpre[j];
      *(bf16x8*)&Vs[c >> 3][(c & 7) * 8]  = vpre[j];
    }
    __syncthreads();
    if (kt + 1 < NT) {
#pragma unroll
      for (int j = 0; j < 4; ++j) {
        const int c = j*256 + tid;
        kpre[j] = *(const bf16x8*)(Kh + (size_t)((kt+1)*64 + (c >> 4)) * HDIM + (c & 15) * 8);
        vpre[j] = *(const bf16x8*)(Vh + (size_t)(c >> 3) * LL + (kt+1)*64 + (c & 7) * 8);
      }
    }
    if (kbase <= q0w + 31) {
      f32x4 s[2][4];
#pragma unroll
      for (int qr = 0; qr < 2; ++qr)
#pragma unroll
        for (int c = 0; c < 4; ++c) s[qr][c] = vzero;
#pragma unroll
      for (int c = 0; c < 4; ++c) {
        bf16x8 kf[4];
#pragma unroll
        for (int kk = 0; kk < 4; ++kk)
          kf[kk] = *(const bf16x8*)&Ks[c*16 + lr][kk*32 + lkg*8];
#pragma unroll
        for (int qr = 0; qr < 2; ++qr)
#pragma unroll
          for (int kk = 0; kk < 4; ++kk)
            s[qr][c] = mfma16(qf[qr][kk], kf[kk], s[qr][c]);
      }
#pragma unroll
      for (int qr = 0; qr < 2; ++qr) {
        float scl4[4];
#pragma unroll
        for (int reg = 0; reg < 4; ++reg) {
          const int row = q0w + qr*16 + lkg*4 + reg;
          float v0 = (kbase      + lr <= row) ? s[qr][0][reg] : -INFINITY;
          float v1 = (kbase + 16 + lr <= row) ? s[qr][1][reg] : -INFINITY;
          float v2 = (kbase + 32 + lr <= row) ? s[qr][2][reg] : -INFINITY;
          float v3 = (kbase + 48 + lr <= row) ? s[qr][3][reg] : -INFINITY;
          float tm = fmaxf(fmaxf(v0, v1), fmaxf(v2, v3));
          tm = fmaxf(tm, __shfl_xor(tm, 1));
          tm = fmaxf(tm, __shfl_xor(tm, 2));
          tm = fmaxf(tm, __shfl_xor(tm, 4));
          tm = fmaxf(tm, __shfl_xor(tm, 8));
          const float mnew = fmaxf(mrow[qr][reg], tm);
          const float scl  = __expf(mrow[qr][reg] - mnew);
          mrow[qr][reg] = mnew;
          float p0 = __expf(v0 - mnew);
          float p1 = __expf(v1 - mnew);
          float p2 = __expf(v2 - mnew);
          float p3 = __expf(v3 - mnew);
          float rs = (p0 + p1) + (p2 + p3);
          rs += __shfl_xor(rs, 1);
          rs += __shfl_xor(rs, 2);
          rs += __shfl_xor(rs, 4);
          rs += __shfl_xor(rs, 8);
          lrow[qr][reg] = lrow[qr][reg] * scl + rs;
          scl4[reg] = scl;
          const int prow = qr*16 + lkg*4 + reg;
          Ps[wid][prow][lr]      = __float2bfloat16(p0);
          Ps[wid][prow][16 + lr] = __float2bfloat16(p1);
          Ps[wid][prow][32 + lr] = __float2bfloat16(p2);
          Ps[wid][prow][48 + lr] = __float2bfloat16(p3);
        }
#pragma unroll
        for (int db = 0; db < 8; ++db) {
          oacc[qr][db][0] *= scl4[0]; oacc[qr][db][1] *= scl4[1];
          oacc[qr][db][2] *= scl4[2]; oacc[qr][db][3] *= scl4[3];
        }
      }
      asm volatile("s_waitcnt lgkmcnt(0)" ::: "memory");
      __builtin_amdgcn_sched_barrier(0);
      bf16x8 pf[2][2];
#pragma unroll
      for (int qr = 0; qr < 2; ++qr)
#pragma unroll
        for (int k2 = 0; k2 < 2; ++k2)
          pf[qr][k2] = *(const bf16x8*)&Ps[wid][qr*16 + lr][k2*32 + lkg*8];
#pragma unroll
      for (int db = 0; db < 8; ++db) {
        bf16x8 vf0 = *(const bf16x8*)&Vs[db*16 + lr][lkg*8];
        bf16x8 vf1 = *(const bf16x8*)&Vs[db*16 + lr][32 + lkg*8];
#pragma unroll
        for (int qr = 0; qr < 2; ++qr) {
          oacc[qr][db] = mfma16(pf[qr][0], vf0, oacc[qr][db]);
          oacc[qr][db] = mfma16(pf[qr][1], vf1, oacc[qr][db]);
        }
      }
    }
  }

  const int b = bh >> 4, h = bh & 15;
#pragma unroll
  for (int qr = 0; qr < 2; ++qr)
#pragma unroll
    for (int reg = 0; reg < 4; ++reg) {
      const float inv = 1.0f / lrow[qr][reg];
      const int row = q0w + qr*16 + lkg*4 + reg;
      bf16* dst = attnA + ((size_t)(b*LL + row)) * MODEL + h * HDIM;
#pragma unroll
      for (int db = 0; db < 8; ++db)
        dst[db*16 + lr] = __float2bfloat16(oacc[qr][db][reg] * inv);
    }
}

// ---------------- launch ----------------
extern "C" void kernel_launch(void* const* d_in, const int* in_sizes, int n_in,
                              void* d_out, int out_size, void* d_ws, size_t ws_size,
                              hipStream_t stream)
{
  const float* x    = (const float*)d_in[0];
  const float* cosT = (const float*)d_in[1];
  const float* sinT = (const float*)d_in[2];
  const float* Wqkv = (const float*)d_in[3];
  const float* Wc   = (const float*)d_in[4];
  const float* bc   = (const float*)d_in[5];
  float* out = (float*)d_out;

  // workspace layout (bytes):
  //   x16    @ 0         : 16,777,216   (reused as attnA later)
  //   WqkvT  @ 16777216  : 25,165,824
  //   WcT    @ 41943040  :  8,388,608
  //   Qb     @ 50331648  : 16,777,216
  //   Kb     @ 67108864  : 16,777,216
  //   VTb    @ 83886080  : 16,777,216   -> total 100,663,296 B
  if (ws_size < 100663296u) return;
  char* w = (char*)d_ws;
  bf16* x16   = (bf16*)(w);
  bf16* WqkvT = (bf16*)(w + (size_t)16777216);
  bf16* WcT   = (bf16*)(w + (size_t)41943040);
  bf16* Qb    = (bf16*)(w + (size_t)50331648);
  bf16* Kb    = (bf16*)(w + (size_t)67108864);
  bf16* VTb   = (bf16*)(w + (size_t)83886080);
  bf16* attnA = x16;   // overlay: x16 dead after GEMM1

  // allow 128KB dynamic LDS (idempotent; not a stream op -> capture-safe)
  hipFuncSetAttribute(reinterpret_cast<const void*>(&k_gemm8<1>),
                      hipFuncAttributeMaxDynamicSharedMemorySize, 131072);
  hipFuncSetAttribute(reinterpret_cast<const void*>(&k_gemm8<2>),
                      hipFuncAttributeMaxDynamicSharedMemorySize, 131072);

  k_cvt<<<(MTOT*MODEL/4 + 255)/256, 256, 0, stream>>>(x, x16, MTOT*MODEL/4);
  k_transpose<<<dim3(N1/32,    MODEL/32), 256, 0, stream>>>(Wqkv, WqkvT, MODEL, N1);
  k_transpose<<<dim3(MODEL/32, MODEL/32), 256, 0, stream>>>(Wc,   WcT,   MODEL, MODEL);

  k_gemm8<1><<<dim3(N1/256, MTOT/256), 512, 131072, stream>>>(
      x16, WqkvT, MTOT, N1, MODEL,
      nullptr, nullptr, Qb, Kb, VTb, cosT, sinT);

  k_attn<<<dim3(LL/128, BB*NHEAD), 256, 0, stream>>>(Qb, Kb, VTb, attnA);

  k_gemm8<2><<<dim3(MODEL/256, MTOT/256), 512, 131072, stream>>>(
      attnA, WcT, MTOT, MODEL, MODEL,
      out, bc, nullptr, nullptr, nullptr, nullptr, nullptr);
}